// Round 4
// baseline (1498.572 us; speedup 1.0000x reference)
//
#include <hip/hip_runtime.h>
#include <hip/hip_bf16.h>
#include <math.h>

// Problem constants (from reference)
#define NB 2
#define NN 2048
#define NJ 24
#define NIB 9
#define NCD 16
#define NHID 128
#define NP (NB * NN)        // 4096
#define NPI (NP * NIB)      // 36864
#define NBSTRIDE (NN * NIB) // 18432 per batch
#define SBLEND 20.0f
#define CVG_EPS 1e-5f
#define MAX_STEPS 50

// LDS strides (gcd(stride,32)==1 -> conflict-free column reads)
#define HSTR 129
#define INSTRD 21
#define LSTR 25

static __device__ __forceinline__ float softplusf(float x) {
    // jax.nn.softplus = logaddexp(x,0) = max(x,0) + log1p(exp(-|x|))
    return fmaxf(x, 0.0f) + log1pf(expf(-fabsf(x)));
}
static __device__ __forceinline__ float sigmoidf(float x) {
    return 1.0f / (1.0f + expf(-x));
}
// init-bone index: {0,1,2,4,5,16,17,18,19}
static __device__ __forceinline__ int bone_of(int ib) {
    return (ib < 3) ? ib : ((ib < 5) ? ib + 1 : ib + 11);
}

// acc[0..31] += sum_k inrow[k] * W[k*NHID + jb + jj]   (W access wave-uniform -> s_load)
template <int K>
static __device__ __forceinline__ void mv_acc32(const float* __restrict__ Wp, const float* inrow,
                                                int jb, float* acc) {
#pragma unroll 4
    for (int k = 0; k < K; k++) {
        float h = inrow[k];
        const float* wk = Wp + k * NHID + jb;
#pragma unroll
        for (int jj = 0; jj < 32; jj++) acc[jj] = fmaf(h, wk[jj], acc[jj]);
    }
}

// value-MLP hidden layer: out = softplus(in @ W + b), written into Hs
template <int K, int LDIN>
static __device__ __forceinline__ void val_layer(const float* __restrict__ Wp,
                                                 const float* __restrict__ bp,
                                                 const float* inbase, float (*Hs)[HSTR], int r,
                                                 int jb, bool prebar) {
    float acc[32];
#pragma unroll
    for (int jj = 0; jj < 32; jj++) acc[jj] = bp[jb + jj];
    mv_acc32<K>(Wp, inbase + r * LDIN, jb, acc);
    if (prebar) __syncthreads();  // all waves done reading before in-place overwrite
#pragma unroll
    for (int jj = 0; jj < 32; jj++) Hs[r][jb + jj] = softplusf(acc[jj]);
    __syncthreads();
}

// jacfwd layer: rows 0..15 = value (softplus), rows 16..63 = tangents (sigmoid(z_val)*z_tan)
template <int K, int LDIN>
static __device__ __forceinline__ void jac_layer(const float* __restrict__ Wp,
                                                 const float* __restrict__ bp,
                                                 const float* inbase, float (*Hs)[HSTR], int r,
                                                 int jb, bool prebar) {
    const bool isval = (r < 16);
    const int p = r & 15;
    float acc[32];
#pragma unroll
    for (int jj = 0; jj < 32; jj++) acc[jj] = isval ? bp[jb + jj] : 0.0f;
    mv_acc32<K>(Wp, inbase + r * LDIN, jb, acc);
    if (prebar) __syncthreads();
    // publish raw pre-activations z
#pragma unroll
    for (int jj = 0; jj < 32; jj++) Hs[r][jb + jj] = acc[jj];
    __syncthreads();
    // tangent rows fetch the value-row z
    float zv[32];
    if (!isval) {
#pragma unroll
        for (int jj = 0; jj < 32; jj++) zv[jj] = Hs[p][jb + jj];
    }
    __syncthreads();
    if (isval) {
#pragma unroll
        for (int jj = 0; jj < 32; jj++) Hs[r][jb + jj] = softplusf(acc[jj]);
    } else {
#pragma unroll
        for (int jj = 0; jj < 32; jj++) Hs[r][jb + jj] = sigmoidf(zv[jj]) * acc[jj];
    }
    __syncthreads();
}

// final LBS layer (128 -> 24 logits), NC cols per wave
template <int NC, int LDW, bool JAC>
static __device__ __forceinline__ void logit_layer(const float* __restrict__ Wp,
                                                   const float* __restrict__ bp,
                                                   const float* inbase, float (*Lgs)[LSTR], int r,
                                                   int wid) {
    const int jb = wid * NC;
    const bool isval = (!JAC) || (r < 16);
    float acc[NC];
#pragma unroll
    for (int jj = 0; jj < NC; jj++) acc[jj] = isval ? bp[jb + jj] : 0.0f;
#pragma unroll 4
    for (int k = 0; k < NHID; k++) {
        float h = inbase[r * HSTR + k];
        const float* wk = Wp + k * LDW + jb;
#pragma unroll
        for (int jj = 0; jj < NC; jj++) acc[jj] = fmaf(h, wk[jj], acc[jj]);
    }
#pragma unroll
    for (int jj = 0; jj < NC; jj++) Lgs[r][jb + jj] = acc[jj];
    __syncthreads();
}

// ---------------------------------------------------------------------------
// Fully fused kernel: 64 problems per block (256 threads, 4 waves).
//   Phase 1 (init): 4 passes; pass ii processes points [ii*16, ii*16+16) through
//     the 64-row (16 value + 48 tangent) jacfwd machinery -> per-thread state.
//   Phase 2 (Broyden): 50 iterations max, block-wide early exit.
//   Phase 3 (disp MLP) + f32 store.  OUTPUT IS FLOAT32 (reference dtype).
// ---------------------------------------------------------------------------
__global__ __launch_bounds__(256) void kernel_fused(
    const float* __restrict__ xd, const float* __restrict__ cond, const float* __restrict__ tfs,
    const float* __restrict__ lw0, const float* __restrict__ lb0,
    const float* __restrict__ lw1, const float* __restrict__ lb1,
    const float* __restrict__ lw2, const float* __restrict__ lb2,
    const float* __restrict__ lw3, const float* __restrict__ lb3,
    const float* __restrict__ dw0, const float* __restrict__ db0,
    const float* __restrict__ dw1, const float* __restrict__ db1,
    const float* __restrict__ dw2, const float* __restrict__ db2,
    const float* __restrict__ dw3, const float* __restrict__ db3,
    float* __restrict__ out) {
    __shared__ float sIN[64][INSTRD];
    __shared__ float sH[64][HSTR];
    __shared__ float sLg[64][LSTR];
    __shared__ float sTm[NJ * 12];
    __shared__ int sFlag;

    const int tid = threadIdx.x;
    const int r = tid & 63;
    const int wid = __builtin_amdgcn_readfirstlane(tid >> 6);
    const int jb = wid * 32;
    const int pi0 = blockIdx.x * 64;
    const int b = pi0 / NBSTRIDE;  // 18432 % 64 == 0 -> batch uniform per block
    const int pi = pi0 + r;        // this thread's problem (valid for tid < 64)

    // top-3 rows of each bone transform into LDS
    for (int t = tid; t < NJ * 12; t += 256) {
        int j = t / 12, rc = t % 12;
        sTm[t] = tfs[(size_t)(b * NJ + j) * 16 + rc];
    }
    // tangent one-hot rows (16..63): d([x,cond])/dx_d = e_d
    if (tid >= 16 && tid < 64) {
        const int d = (tid >> 4) - 1;
#pragma unroll
        for (int k = 0; k < 19; k++) sIN[tid][k] = (k == d) ? 1.0f : 0.0f;
    }
    // cond for value rows 0..15 (persists across passes; passes rewrite only cols 0..2)
    if (tid < 16) {
#pragma unroll
        for (int cc = 0; cc < NCD; cc++) sIN[tid][3 + cc] = cond[b * NCD + cc];
    }

    // per-thread persistent Broyden state (meaningful for tid < 64)
    float x0_ = 0, x1_ = 0, x2_ = 0, g0 = 0, g1 = 0, g2 = 0;
    float Ji0 = 0, Ji1 = 0, Ji2 = 0, Ji3 = 0, Ji4 = 0, Ji5 = 0, Ji6 = 0, Ji7 = 0, Ji8 = 0;
    float u0 = 0, u1 = 0, u2 = 0, bx0 = 0, bx1 = 0, bx2 = 0, berr = 0;
    float tx = 0, ty = 0, tz = 0;
    if (tid < 64) {
        const int pp = pi / NIB;
        tx = xd[pp * 3 + 0]; ty = xd[pp * 3 + 1]; tz = xd[pp * 3 + 2];
    }

    // ---------------- Phase 1: init (x0, g(x0), jacfwd J, J^-1, upd0) ----------------
#pragma unroll 1
    for (int pass = 0; pass < 4; ++pass) {
        __syncthreads();  // previous pass fully done with sIN/sH/sLg
        if ((tid >> 4) == pass) {  // 16 threads: this pass's points; p = tid & 15
            const int p = tid & 15;
            const int ib = pi % NIB;
            const int bone = bone_of(ib);
            const float* T = tfs + (size_t)(b * NJ + bone) * 16;
            float r00 = T[0], r01 = T[1], r02 = T[2], t0 = T[3];
            float r10 = T[4], r11 = T[5], r12 = T[6], t1 = T[7];
            float r20 = T[8], r21 = T[9], r22 = T[10], t2 = T[11];
            float det = r00 * (r11 * r22 - r12 * r21) - r01 * (r10 * r22 - r12 * r20) +
                        r02 * (r10 * r21 - r11 * r20);
            float rd = 1.0f / det;
            float i00 = (r11 * r22 - r12 * r21) * rd, i01 = -(r01 * r22 - r02 * r21) * rd,
                  i02 = (r01 * r12 - r02 * r11) * rd;
            float i10 = -(r10 * r22 - r12 * r20) * rd, i11 = (r00 * r22 - r02 * r20) * rd,
                  i12 = -(r00 * r12 - r02 * r10) * rd;
            float i20 = (r10 * r21 - r11 * r20) * rd, i21 = -(r00 * r21 - r01 * r20) * rd,
                  i22 = (r00 * r11 - r01 * r10) * rd;
            float vx = tx - t0, vy = ty - t1, vz = tz - t2;
            x0_ = i00 * vx + i01 * vy + i02 * vz;
            x1_ = i10 * vx + i11 * vy + i12 * vz;
            x2_ = i20 * vx + i21 * vy + i22 * vz;
            sIN[p][0] = x0_; sIN[p][1] = x1_; sIN[p][2] = x2_;
        }
        __syncthreads();

        jac_layer<19, INSTRD>(lw0, lb0, &sIN[0][0], sH, r, jb, false);
        jac_layer<NHID, HSTR>(lw1, lb1, &sH[0][0], sH, r, jb, true);
        jac_layer<NHID, HSTR>(lw2, lb2, &sH[0][0], sH, r, jb, true);
        logit_layer<6, NJ, true>(lw3, lb3, &sH[0][0], sLg, r, wid);

        if ((tid >> 4) == pass) {
            const int p = tid & 15;
            float mx = -1e30f;
#pragma unroll
            for (int j = 0; j < NJ; j++) mx = fmaxf(mx, SBLEND * sLg[p][j]);
            float S = 0.0f;
#pragma unroll
            for (int j = 0; j < NJ; j++) S += expf(SBLEND * sLg[p][j] - mx);
            const float invS = 1.0f / S;
            float d0 = 0, d1 = 0, d2 = 0;  // sum_j s_j * (SBLEND * u_{j,d})
#pragma unroll
            for (int j = 0; j < NJ; j++) {
                float sj = expf(SBLEND * sLg[p][j] - mx) * invS;
                d0 += sj * (SBLEND * sLg[16 + p][j]);
                d1 += sj * (SBLEND * sLg[32 + p][j]);
                d2 += sj * (SBLEND * sLg[48 + p][j]);
            }
            float f0 = 0, f1 = 0, f2 = 0;
            float J00 = 0, J01 = 0, J02 = 0, J10 = 0, J11 = 0, J12 = 0, J20 = 0, J21 = 0,
                  J22 = 0;
#pragma unroll
            for (int j = 0; j < NJ; j++) {
                float sj = expf(SBLEND * sLg[p][j] - mx) * invS;
                float uj0 = SBLEND * sLg[16 + p][j], uj1 = SBLEND * sLg[32 + p][j],
                      uj2 = SBLEND * sLg[48 + p][j];
                float sd0 = sj * (uj0 - d0), sd1 = sj * (uj1 - d1), sd2 = sj * (uj2 - d2);
                const float* M = &sTm[j * 12];
                float y0 = M[0] * x0_ + M[1] * x1_ + M[2] * x2_ + M[3];
                float y1 = M[4] * x0_ + M[5] * x1_ + M[6] * x2_ + M[7];
                float y2 = M[8] * x0_ + M[9] * x1_ + M[10] * x2_ + M[11];
                f0 += sj * y0; f1 += sj * y1; f2 += sj * y2;
                J00 += sd0 * y0 + sj * M[0]; J01 += sd1 * y0 + sj * M[1]; J02 += sd2 * y0 + sj * M[2];
                J10 += sd0 * y1 + sj * M[4]; J11 += sd1 * y1 + sj * M[5]; J12 += sd2 * y1 + sj * M[6];
                J20 += sd0 * y2 + sj * M[8]; J21 += sd1 * y2 + sj * M[9]; J22 += sd2 * y2 + sj * M[10];
            }
            g0 = f0 - tx; g1 = f1 - ty; g2 = f2 - tz;
            float detJ = J00 * (J11 * J22 - J12 * J21) - J01 * (J10 * J22 - J12 * J20) +
                         J02 * (J10 * J21 - J11 * J20);
            float rdJ = 1.0f / detJ;
            Ji0 = (J11 * J22 - J12 * J21) * rdJ; Ji1 = -(J01 * J22 - J02 * J21) * rdJ;
            Ji2 = (J01 * J12 - J02 * J11) * rdJ;
            Ji3 = -(J10 * J22 - J12 * J20) * rdJ; Ji4 = (J00 * J22 - J02 * J20) * rdJ;
            Ji5 = -(J00 * J12 - J02 * J10) * rdJ;
            Ji6 = (J10 * J21 - J11 * J20) * rdJ; Ji7 = -(J00 * J21 - J01 * J20) * rdJ;
            Ji8 = (J00 * J11 - J01 * J10) * rdJ;
            u0 = -(Ji0 * g0 + Ji1 * g1 + Ji2 * g2);
            u1 = -(Ji3 * g0 + Ji4 * g1 + Ji5 * g2);
            u2 = -(Ji6 * g0 + Ji7 * g1 + Ji8 * g2);
            berr = sqrtf(g0 * g0 + g1 * g1 + g2 * g2);
            bx0 = x0_; bx1 = x1_; bx2 = x2_;
        }
    }

    // ---------------- Phase 2: Broyden loop (state in wave-0 registers) ----------------
    if (tid < 64) {
#pragma unroll
        for (int cc = 0; cc < NCD; cc++) sIN[tid][3 + cc] = cond[b * NCD + cc];
    }

#pragma unroll 1
    for (int it = 0; it < MAX_STEPS; ++it) {
        float dx0 = 0, dx1 = 0, dx2 = 0;
        if (tid < 64) {
            dx0 = u0; dx1 = u1; dx2 = u2;
            x0_ += dx0; x1_ += dx1; x2_ += dx2;
            sIN[tid][0] = x0_; sIN[tid][1] = x1_; sIN[tid][2] = x2_;
        }
        __syncthreads();

        val_layer<19, INSTRD>(lw0, lb0, &sIN[0][0], sH, r, jb, false);
        val_layer<NHID, HSTR>(lw1, lb1, &sH[0][0], sH, r, jb, true);
        val_layer<NHID, HSTR>(lw2, lb2, &sH[0][0], sH, r, jb, true);
        logit_layer<6, NJ, false>(lw3, lb3, &sH[0][0], sLg, r, wid);

        if (tid < 64) {
            float mx = -1e30f;
#pragma unroll
            for (int j = 0; j < NJ; j++) mx = fmaxf(mx, SBLEND * sLg[r][j]);
            float S = 0.0f;
#pragma unroll
            for (int j = 0; j < NJ; j++) {
                float e = expf(SBLEND * sLg[r][j] - mx);
                sLg[r][j] = e;
                S += e;
            }
            const float invS = 1.0f / S;
            float f0 = 0, f1 = 0, f2 = 0;
#pragma unroll
            for (int j = 0; j < NJ; j++) {
                float sj = sLg[r][j] * invS;
                const float* M = &sTm[j * 12];
                f0 += sj * (M[0] * x0_ + M[1] * x1_ + M[2] * x2_ + M[3]);
                f1 += sj * (M[4] * x0_ + M[5] * x1_ + M[6] * x2_ + M[7]);
                f2 += sj * (M[8] * x0_ + M[9] * x1_ + M[10] * x2_ + M[11]);
            }
            float gn0 = f0 - tx, gn1 = f1 - ty, gn2 = f2 - tz;
            float dg0 = gn0 - g0, dg1 = gn1 - g1, dg2 = gn2 - g2;
            float Jd0 = Ji0 * dg0 + Ji1 * dg1 + Ji2 * dg2;
            float Jd1 = Ji3 * dg0 + Ji4 * dg1 + Ji5 * dg2;
            float Jd2 = Ji6 * dg0 + Ji7 * dg1 + Ji8 * dg2;
            float v0 = dx0 * Ji0 + dx1 * Ji3 + dx2 * Ji6;
            float v1 = dx0 * Ji1 + dx1 * Ji4 + dx2 * Ji7;
            float v2 = dx0 * Ji2 + dx1 * Ji5 + dx2 * Ji8;
            float a0 = dx0 - Jd0, a1 = dx1 - Jd1, a2 = dx2 - Jd2;
            float bden = v0 * dg0 + v1 * dg1 + v2 * dg2 + 1e-6f;
            float s0 = a0 / bden, s1 = a1 / bden, s2 = a2 / bden;
            Ji0 += s0 * v0; Ji1 += s0 * v1; Ji2 += s0 * v2;
            Ji3 += s1 * v0; Ji4 += s1 * v1; Ji5 += s1 * v2;
            Ji6 += s2 * v0; Ji7 += s2 * v1; Ji8 += s2 * v2;
            u0 = -(Ji0 * gn0 + Ji1 * gn1 + Ji2 * gn2);
            u1 = -(Ji3 * gn0 + Ji4 * gn1 + Ji5 * gn2);
            u2 = -(Ji6 * gn0 + Ji7 * gn1 + Ji8 * gn2);
            float err = sqrtf(gn0 * gn0 + gn1 * gn1 + gn2 * gn2);
            if (err < berr) { berr = err; bx0 = x0_; bx1 = x1_; bx2 = x2_; }
            g0 = gn0; g1 = gn1; g2 = gn2;
            int allc = __all(berr < CVG_EPS);
            if (tid == 0) sFlag = allc;
        }
        __syncthreads();
        if (sFlag) break;
    }

    // ---------------- Phase 3: disp MLP + output (float32) ----------------
    if (tid < 64) {
        sIN[tid][0] = bx0; sIN[tid][1] = bx1; sIN[tid][2] = bx2;  // cond cols already set
    }
    __syncthreads();

    val_layer<19, INSTRD>(dw0, db0, &sIN[0][0], sH, r, jb, false);
    val_layer<NHID, HSTR>(dw1, db1, &sH[0][0], sH, r, jb, true);
    val_layer<NHID, HSTR>(dw2, db2, &sH[0][0], sH, r, jb, true);

    if (tid < 64) {
        float a0 = db3[0], a1 = db3[1], a2 = db3[2];
#pragma unroll 4
        for (int k = 0; k < NHID; k++) {
            float h = sH[tid][k];
            a0 = fmaf(h, dw3[k * 3 + 0], a0);
            a1 = fmaf(h, dw3[k * 3 + 1], a1);
            a2 = fmaf(h, dw3[k * 3 + 2], a2);
        }
        out[pi * 3 + 0] = bx0 + a0;
        out[pi * 3 + 1] = bx1 + a1;
        out[pi * 3 + 2] = bx2 + a2;
        out[3 * NPI + pi] = (berr < CVG_EPS) ? 1.0f : 0.0f;
    }
}

extern "C" void kernel_launch(void* const* d_in, const int* in_sizes, int n_in,
                              void* d_out, int out_size, void* d_ws, size_t ws_size,
                              hipStream_t stream) {
    (void)in_sizes; (void)n_in; (void)out_size; (void)d_ws; (void)ws_size;
    const float* xd   = (const float*)d_in[0];
    const float* cond = (const float*)d_in[1];
    const float* tfs  = (const float*)d_in[2];
    const float* lw0 = (const float*)d_in[3];  const float* lb0 = (const float*)d_in[4];
    const float* lw1 = (const float*)d_in[5];  const float* lb1 = (const float*)d_in[6];
    const float* lw2 = (const float*)d_in[7];  const float* lb2 = (const float*)d_in[8];
    const float* lw3 = (const float*)d_in[9];  const float* lb3 = (const float*)d_in[10];
    const float* dw0 = (const float*)d_in[11]; const float* db0 = (const float*)d_in[12];
    const float* dw1 = (const float*)d_in[13]; const float* db1 = (const float*)d_in[14];
    const float* dw2 = (const float*)d_in[15]; const float* db2 = (const float*)d_in[16];
    const float* dw3 = (const float*)d_in[17]; const float* db3 = (const float*)d_in[18];
    float* out = (float*)d_out;

    kernel_fused<<<NPI / 64, 256, 0, stream>>>(xd, cond, tfs, lw0, lb0, lw1, lb1, lw2, lb2,
                                               lw3, lb3, dw0, db0, dw1, db1, dw2, db2, dw3, db3,
                                               out);
}

// Round 5
// 1246.789 us; speedup vs baseline: 1.2019x; 1.2019x over previous
//
#include <hip/hip_runtime.h>
#include <math.h>

// Problem constants (from reference)
#define NB 2
#define NN 2048
#define NJ 24
#define NIB 9
#define NCD 16
#define NHID 128
#define NP (NB * NN)        // 4096
#define NPI (NP * NIB)      // 36864
#define NBSTRIDE (NN * NIB) // 18432 per batch
#define SBLEND 20.0f
#define CVG_EPS 1e-5f
#define MAX_STEPS 50
#define THRESH 16           // offload to phase B when <= this many rows unconverged

// LDS strides (gcd(stride,32)==1 -> conflict-free column reads)
#define HSTR 129
#define INSTRD 21
#define LSTR 25

// ws layout (float offsets). cnt ints at [0,1]; capacity ~2.95 MB total.
#define WS_BX 4
#define WS_BE (4 + 3 * NPI)
#define WS_META (4 + 4 * NPI)  // int region, NPI entries
#define WS_ST (4 + 5 * NPI)    // 15 components x NPI (SoA)

static __device__ __forceinline__ float softplusf(float x) {
    return fmaxf(x, 0.0f) + log1pf(expf(-fabsf(x)));
}
static __device__ __forceinline__ float sigmoidf(float x) {
    return 1.0f / (1.0f + expf(-x));
}
// init-bone index: {0,1,2,4,5,16,17,18,19}
static __device__ __forceinline__ int bone_of(int ib) {
    return (ib < 3) ? ib : ((ib < 5) ? ib + 1 : ib + 11);
}

// acc[0..15] += sum_k inrow[k] * W[k*NHID + jb + jj]  (wave-uniform W -> s_load)
template <int K>
static __device__ __forceinline__ void mv_acc16(const float* __restrict__ Wp, const float* inrow,
                                                int jb, float* acc) {
#pragma unroll 4
    for (int k = 0; k < K; k++) {
        float h = inrow[k];
        const float* wk = Wp + k * NHID + jb;
#pragma unroll
        for (int jj = 0; jj < 16; jj++) acc[jj] = fmaf(h, wk[jj], acc[jj]);
    }
}

template <int K, int LDIN>
static __device__ __forceinline__ void val_layer(const float* __restrict__ Wp,
                                                 const float* __restrict__ bp,
                                                 const float* inbase, float (*Hs)[HSTR], int r,
                                                 int jb, bool prebar) {
    float acc[16];
#pragma unroll
    for (int jj = 0; jj < 16; jj++) acc[jj] = bp[jb + jj];
    mv_acc16<K>(Wp, inbase + r * LDIN, jb, acc);
    if (prebar) __syncthreads();
#pragma unroll
    for (int jj = 0; jj < 16; jj++) Hs[r][jb + jj] = softplusf(acc[jj]);
    __syncthreads();
}

// jacfwd layer: rows 0..15 = value (softplus), rows 16..63 = tangents (sigmoid(zv)*z)
template <int K, int LDIN>
static __device__ __forceinline__ void jac_layer(const float* __restrict__ Wp,
                                                 const float* __restrict__ bp,
                                                 const float* inbase, float (*Hs)[HSTR], int r,
                                                 int jb, bool prebar) {
    const bool isval = (r < 16);
    const int p = r & 15;
    float acc[16];
#pragma unroll
    for (int jj = 0; jj < 16; jj++) acc[jj] = isval ? bp[jb + jj] : 0.0f;
    mv_acc16<K>(Wp, inbase + r * LDIN, jb, acc);
    if (prebar) __syncthreads();
#pragma unroll
    for (int jj = 0; jj < 16; jj++) Hs[r][jb + jj] = acc[jj];  // publish raw z
    __syncthreads();
    float zv[16];
    if (!isval) {
#pragma unroll
        for (int jj = 0; jj < 16; jj++) zv[jj] = Hs[p][jb + jj];
    }
    __syncthreads();
    if (isval) {
#pragma unroll
        for (int jj = 0; jj < 16; jj++) Hs[r][jb + jj] = softplusf(acc[jj]);
    } else {
#pragma unroll
        for (int jj = 0; jj < 16; jj++) Hs[r][jb + jj] = sigmoidf(zv[jj]) * acc[jj];
    }
    __syncthreads();
}

// final LBS layer (128 -> 24 logits), 3 cols per wave (8 waves)
template <bool JAC>
static __device__ __forceinline__ void logit_layer(const float* __restrict__ Wp,
                                                   const float* __restrict__ bp,
                                                   const float* inbase, float (*Lgs)[LSTR], int r,
                                                   int wid) {
    const int jb = wid * 3;
    const bool isval = (!JAC) || (r < 16);
    float acc[3];
#pragma unroll
    for (int jj = 0; jj < 3; jj++) acc[jj] = isval ? bp[jb + jj] : 0.0f;
#pragma unroll 4
    for (int k = 0; k < NHID; k++) {
        float h = inbase[r * HSTR + k];
        const float* wk = Wp + k * NJ + jb;
#pragma unroll
        for (int jj = 0; jj < 3; jj++) acc[jj] = fmaf(h, wk[jj], acc[jj]);
    }
#pragma unroll
    for (int jj = 0; jj < 3; jj++) Lgs[r][jb + jj] = acc[jj];
    __syncthreads();
}

// One Broyden update from logits in sLgRow (row r). Returns via refs.
static __device__ __forceinline__ void broyden_step(
    float* sLgRow, const float* sTm, float tx, float ty, float tz,
    float dx0, float dx1, float dx2,
    float& x0_, float& x1_, float& x2_, float& g0, float& g1, float& g2,
    float& Ji0, float& Ji1, float& Ji2, float& Ji3, float& Ji4, float& Ji5,
    float& Ji6, float& Ji7, float& Ji8,
    float& u0, float& u1, float& u2,
    float& bx0, float& bx1, float& bx2, float& berr) {
    float mx = -1e30f;
#pragma unroll
    for (int j = 0; j < NJ; j++) mx = fmaxf(mx, SBLEND * sLgRow[j]);
    float S = 0.0f;
#pragma unroll
    for (int j = 0; j < NJ; j++) {
        float e = expf(SBLEND * sLgRow[j] - mx);
        sLgRow[j] = e;
        S += e;
    }
    const float invS = 1.0f / S;
    float f0 = 0, f1 = 0, f2 = 0;
#pragma unroll
    for (int j = 0; j < NJ; j++) {
        float sj = sLgRow[j] * invS;
        const float* M = &sTm[j * 12];
        f0 += sj * (M[0] * x0_ + M[1] * x1_ + M[2] * x2_ + M[3]);
        f1 += sj * (M[4] * x0_ + M[5] * x1_ + M[6] * x2_ + M[7]);
        f2 += sj * (M[8] * x0_ + M[9] * x1_ + M[10] * x2_ + M[11]);
    }
    float gn0 = f0 - tx, gn1 = f1 - ty, gn2 = f2 - tz;
    float dg0 = gn0 - g0, dg1 = gn1 - g1, dg2 = gn2 - g2;
    float Jd0 = Ji0 * dg0 + Ji1 * dg1 + Ji2 * dg2;
    float Jd1 = Ji3 * dg0 + Ji4 * dg1 + Ji5 * dg2;
    float Jd2 = Ji6 * dg0 + Ji7 * dg1 + Ji8 * dg2;
    float v0 = dx0 * Ji0 + dx1 * Ji3 + dx2 * Ji6;
    float v1 = dx0 * Ji1 + dx1 * Ji4 + dx2 * Ji7;
    float v2 = dx0 * Ji2 + dx1 * Ji5 + dx2 * Ji8;
    float a0 = dx0 - Jd0, a1 = dx1 - Jd1, a2 = dx2 - Jd2;
    float bden = v0 * dg0 + v1 * dg1 + v2 * dg2 + 1e-6f;
    float s0 = a0 / bden, s1 = a1 / bden, s2 = a2 / bden;
    Ji0 += s0 * v0; Ji1 += s0 * v1; Ji2 += s0 * v2;
    Ji3 += s1 * v0; Ji4 += s1 * v1; Ji5 += s1 * v2;
    Ji6 += s2 * v0; Ji7 += s2 * v1; Ji8 += s2 * v2;
    u0 = -(Ji0 * gn0 + Ji1 * gn1 + Ji2 * gn2);
    u1 = -(Ji3 * gn0 + Ji4 * gn1 + Ji5 * gn2);
    u2 = -(Ji6 * gn0 + Ji7 * gn1 + Ji8 * gn2);
    float err = sqrtf(gn0 * gn0 + gn1 * gn1 + gn2 * gn2);
    if (err < berr) { berr = err; bx0 = x0_; bx1 = x1_; bx2 = x2_; }
    g0 = gn0; g1 = gn1; g2 = gn2;
}

// ---------------------------------------------------------------------------
// Phase A: init + Broyden until block has <= THRESH unconverged rows (or done).
// 512 threads = 64 rows x 8 col-waves of 16. Offloads stragglers to ws lists.
// ---------------------------------------------------------------------------
__global__ __launch_bounds__(512) void kernel_a(
    const float* __restrict__ xd, const float* __restrict__ cond, const float* __restrict__ tfs,
    const float* __restrict__ lw0, const float* __restrict__ lb0,
    const float* __restrict__ lw1, const float* __restrict__ lb1,
    const float* __restrict__ lw2, const float* __restrict__ lb2,
    const float* __restrict__ lw3, const float* __restrict__ lb3,
    float* __restrict__ ws) {
    __shared__ float sIN[64][INSTRD];
    __shared__ float sH[64][HSTR];
    __shared__ float sLg[64][LSTR];
    __shared__ float sTm[NJ * 12];
    __shared__ int sCnt;

    const int tid = threadIdx.x;
    const int r = tid & 63;
    const int wid = __builtin_amdgcn_readfirstlane(tid >> 6);
    const int jb = wid * 16;
    const int pi0 = blockIdx.x * 64;
    const int b = pi0 / NBSTRIDE;
    const int pi = pi0 + r;

    for (int t = tid; t < NJ * 12; t += 512) {
        int j = t / 12, rc = t % 12;
        sTm[t] = tfs[(size_t)(b * NJ + j) * 16 + rc];
    }
    if (tid >= 16 && tid < 64) {  // tangent one-hot rows for init passes
        const int d = (tid >> 4) - 1;
#pragma unroll
        for (int k = 0; k < 19; k++) sIN[tid][k] = (k == d) ? 1.0f : 0.0f;
    }
    if (tid < 16) {
#pragma unroll
        for (int cc = 0; cc < NCD; cc++) sIN[tid][3 + cc] = cond[b * NCD + cc];
    }

    float x0_ = 0, x1_ = 0, x2_ = 0, g0 = 0, g1 = 0, g2 = 0;
    float Ji0 = 0, Ji1 = 0, Ji2 = 0, Ji3 = 0, Ji4 = 0, Ji5 = 0, Ji6 = 0, Ji7 = 0, Ji8 = 0;
    float u0 = 0, u1 = 0, u2 = 0, bx0 = 0, bx1 = 0, bx2 = 0, berr = 0;
    float tx = 0, ty = 0, tz = 0;
    if (tid < 64) {
        const int pp = pi / NIB;
        tx = xd[pp * 3 + 0]; ty = xd[pp * 3 + 1]; tz = xd[pp * 3 + 2];
    }

    // ---- init: 4 jacfwd passes of 16 points ----
#pragma unroll 1
    for (int pass = 0; pass < 4; ++pass) {
        __syncthreads();
        if (tid < 64 && (tid >> 4) == pass) {
            const int p = tid & 15;
            const int ib = pi % NIB;
            const float* T = tfs + (size_t)(b * NJ + bone_of(ib)) * 16;
            float r00 = T[0], r01 = T[1], r02 = T[2], t0 = T[3];
            float r10 = T[4], r11 = T[5], r12 = T[6], t1 = T[7];
            float r20 = T[8], r21 = T[9], r22 = T[10], t2 = T[11];
            float det = r00 * (r11 * r22 - r12 * r21) - r01 * (r10 * r22 - r12 * r20) +
                        r02 * (r10 * r21 - r11 * r20);
            float rd = 1.0f / det;
            float i00 = (r11 * r22 - r12 * r21) * rd, i01 = -(r01 * r22 - r02 * r21) * rd,
                  i02 = (r01 * r12 - r02 * r11) * rd;
            float i10 = -(r10 * r22 - r12 * r20) * rd, i11 = (r00 * r22 - r02 * r20) * rd,
                  i12 = -(r00 * r12 - r02 * r10) * rd;
            float i20 = (r10 * r21 - r11 * r20) * rd, i21 = -(r00 * r21 - r01 * r20) * rd,
                  i22 = (r00 * r11 - r01 * r10) * rd;
            float vx = tx - t0, vy = ty - t1, vz = tz - t2;
            x0_ = i00 * vx + i01 * vy + i02 * vz;
            x1_ = i10 * vx + i11 * vy + i12 * vz;
            x2_ = i20 * vx + i21 * vy + i22 * vz;
            sIN[p][0] = x0_; sIN[p][1] = x1_; sIN[p][2] = x2_;
        }
        __syncthreads();

        jac_layer<19, INSTRD>(lw0, lb0, &sIN[0][0], sH, r, jb, false);
        jac_layer<NHID, HSTR>(lw1, lb1, &sH[0][0], sH, r, jb, true);
        jac_layer<NHID, HSTR>(lw2, lb2, &sH[0][0], sH, r, jb, true);
        logit_layer<true>(lw3, lb3, &sH[0][0], sLg, r, wid);

        if (tid < 64 && (tid >> 4) == pass) {
            const int p = tid & 15;
            float mx = -1e30f;
#pragma unroll
            for (int j = 0; j < NJ; j++) mx = fmaxf(mx, SBLEND * sLg[p][j]);
            float S = 0.0f;
#pragma unroll
            for (int j = 0; j < NJ; j++) S += expf(SBLEND * sLg[p][j] - mx);
            const float invS = 1.0f / S;
            float d0 = 0, d1 = 0, d2 = 0;
#pragma unroll
            for (int j = 0; j < NJ; j++) {
                float sj = expf(SBLEND * sLg[p][j] - mx) * invS;
                d0 += sj * (SBLEND * sLg[16 + p][j]);
                d1 += sj * (SBLEND * sLg[32 + p][j]);
                d2 += sj * (SBLEND * sLg[48 + p][j]);
            }
            float f0 = 0, f1 = 0, f2 = 0;
            float J00 = 0, J01 = 0, J02 = 0, J10 = 0, J11 = 0, J12 = 0, J20 = 0, J21 = 0,
                  J22 = 0;
#pragma unroll
            for (int j = 0; j < NJ; j++) {
                float sj = expf(SBLEND * sLg[p][j] - mx) * invS;
                float uj0 = SBLEND * sLg[16 + p][j], uj1 = SBLEND * sLg[32 + p][j],
                      uj2 = SBLEND * sLg[48 + p][j];
                float sd0 = sj * (uj0 - d0), sd1 = sj * (uj1 - d1), sd2 = sj * (uj2 - d2);
                const float* M = &sTm[j * 12];
                float y0 = M[0] * x0_ + M[1] * x1_ + M[2] * x2_ + M[3];
                float y1 = M[4] * x0_ + M[5] * x1_ + M[6] * x2_ + M[7];
                float y2 = M[8] * x0_ + M[9] * x1_ + M[10] * x2_ + M[11];
                f0 += sj * y0; f1 += sj * y1; f2 += sj * y2;
                J00 += sd0 * y0 + sj * M[0]; J01 += sd1 * y0 + sj * M[1]; J02 += sd2 * y0 + sj * M[2];
                J10 += sd0 * y1 + sj * M[4]; J11 += sd1 * y1 + sj * M[5]; J12 += sd2 * y1 + sj * M[6];
                J20 += sd0 * y2 + sj * M[8]; J21 += sd1 * y2 + sj * M[9]; J22 += sd2 * y2 + sj * M[10];
            }
            g0 = f0 - tx; g1 = f1 - ty; g2 = f2 - tz;
            float detJ = J00 * (J11 * J22 - J12 * J21) - J01 * (J10 * J22 - J12 * J20) +
                         J02 * (J10 * J21 - J11 * J20);
            float rdJ = 1.0f / detJ;
            Ji0 = (J11 * J22 - J12 * J21) * rdJ; Ji1 = -(J01 * J22 - J02 * J21) * rdJ;
            Ji2 = (J01 * J12 - J02 * J11) * rdJ;
            Ji3 = -(J10 * J22 - J12 * J20) * rdJ; Ji4 = (J00 * J22 - J02 * J20) * rdJ;
            Ji5 = -(J00 * J12 - J02 * J10) * rdJ;
            Ji6 = (J10 * J21 - J11 * J20) * rdJ; Ji7 = -(J00 * J21 - J01 * J20) * rdJ;
            Ji8 = (J00 * J11 - J01 * J10) * rdJ;
            u0 = -(Ji0 * g0 + Ji1 * g1 + Ji2 * g2);
            u1 = -(Ji3 * g0 + Ji4 * g1 + Ji5 * g2);
            u2 = -(Ji6 * g0 + Ji7 * g1 + Ji8 * g2);
            berr = sqrtf(g0 * g0 + g1 * g1 + g2 * g2);
            bx0 = x0_; bx1 = x1_; bx2 = x2_;
        }
    }

    // ---- Broyden loop with per-problem convergence + straggler offload ----
    if (tid < 64) {
#pragma unroll
        for (int cc = 0; cc < NCD; cc++) sIN[tid][3 + cc] = cond[b * NCD + cc];
    }

    int itdone = MAX_STEPS;
#pragma unroll 1
    for (int it = 0; it < MAX_STEPS; ++it) {
        float dx0 = 0, dx1 = 0, dx2 = 0;
        if (tid < 64) {
            dx0 = u0; dx1 = u1; dx2 = u2;
            x0_ += dx0; x1_ += dx1; x2_ += dx2;
            sIN[tid][0] = x0_; sIN[tid][1] = x1_; sIN[tid][2] = x2_;
        }
        __syncthreads();

        val_layer<19, INSTRD>(lw0, lb0, &sIN[0][0], sH, r, jb, false);
        val_layer<NHID, HSTR>(lw1, lb1, &sH[0][0], sH, r, jb, true);
        val_layer<NHID, HSTR>(lw2, lb2, &sH[0][0], sH, r, jb, true);
        logit_layer<false>(lw3, lb3, &sH[0][0], sLg, r, wid);

        if (tid < 64) {
            broyden_step(&sLg[r][0], sTm, tx, ty, tz, dx0, dx1, dx2,
                         x0_, x1_, x2_, g0, g1, g2,
                         Ji0, Ji1, Ji2, Ji3, Ji4, Ji5, Ji6, Ji7, Ji8,
                         u0, u1, u2, bx0, bx1, bx2, berr);
            unsigned long long m = __ballot(!(berr < CVG_EPS));
            if (tid == 0) sCnt = (int)__popcll(m);
        }
        __syncthreads();
        if (sCnt <= THRESH) { itdone = it + 1; break; }
    }

    if (tid < 64) {
        ws[WS_BX + pi * 3 + 0] = bx0;
        ws[WS_BX + pi * 3 + 1] = bx1;
        ws[WS_BX + pi * 3 + 2] = bx2;
        ws[WS_BE + pi] = berr;
        const int remaining = MAX_STEPS - itdone;
        if (remaining > 0 && !(berr < CVG_EPS)) {
            int idx = atomicAdd((int*)ws + b, 1);
            int slot = b * NBSTRIDE + idx;
            ((int*)ws)[WS_META + slot] = pi | (remaining << 20);
            float st[15] = {x0_, x1_, x2_, g0, g1, g2, Ji0, Ji1, Ji2, Ji3, Ji4, Ji5, Ji6, Ji7, Ji8};
#pragma unroll
            for (int c = 0; c < 15; c++) ws[WS_ST + c * NPI + slot] = st[c];
        }
    }
}

// ---------------------------------------------------------------------------
// Phase B: compacted stragglers, 64 per block, per-row remaining-iteration mask.
// Grid: 576 blocks; first 288 serve batch 0, rest batch 1.
// ---------------------------------------------------------------------------
__global__ __launch_bounds__(512) void kernel_b(
    const float* __restrict__ xd, const float* __restrict__ cond, const float* __restrict__ tfs,
    const float* __restrict__ lw0, const float* __restrict__ lb0,
    const float* __restrict__ lw1, const float* __restrict__ lb1,
    const float* __restrict__ lw2, const float* __restrict__ lb2,
    const float* __restrict__ lw3, const float* __restrict__ lb3,
    float* __restrict__ ws) {
    const int bid = blockIdx.x;
    const int batch = (bid < 288) ? 0 : 1;
    const int chunk0 = (bid - batch * 288) * 64;
    const int S = ((const int*)ws)[batch];
    if (chunk0 >= S) return;  // uniform per block, before any barrier

    __shared__ float sIN[64][INSTRD];
    __shared__ float sH[64][HSTR];
    __shared__ float sLg[64][LSTR];
    __shared__ float sTm[NJ * 12];
    __shared__ int sCnt;

    const int tid = threadIdx.x;
    const int r = tid & 63;
    const int wid = __builtin_amdgcn_readfirstlane(tid >> 6);
    const int jb = wid * 16;

    for (int t = tid; t < NJ * 12; t += 512) {
        int j = t / 12, rc = t % 12;
        sTm[t] = tfs[(size_t)(batch * NJ + j) * 16 + rc];
    }

    float x0_ = 0, x1_ = 0, x2_ = 0, g0 = 0, g1 = 0, g2 = 0;
    float Ji0 = 1, Ji1 = 0, Ji2 = 0, Ji3 = 0, Ji4 = 1, Ji5 = 0, Ji6 = 0, Ji7 = 0, Ji8 = 1;
    float u0 = 0, u1 = 0, u2 = 0, bx0 = 0, bx1 = 0, bx2 = 0, berr = 0;
    float tx = 0, ty = 0, tz = 0;
    int pi = -1, itleft = 0;
    bool realrow = false;
    if (tid < 64) {
        const int k = chunk0 + r;
        realrow = (k < S);
        if (realrow) {
            const int slot = batch * NBSTRIDE + k;
            const int meta = ((const int*)ws)[WS_META + slot];
            pi = meta & 0xFFFFF;
            itleft = meta >> 20;
            x0_ = ws[WS_ST + 0 * NPI + slot]; x1_ = ws[WS_ST + 1 * NPI + slot];
            x2_ = ws[WS_ST + 2 * NPI + slot];
            g0 = ws[WS_ST + 3 * NPI + slot]; g1 = ws[WS_ST + 4 * NPI + slot];
            g2 = ws[WS_ST + 5 * NPI + slot];
            Ji0 = ws[WS_ST + 6 * NPI + slot]; Ji1 = ws[WS_ST + 7 * NPI + slot];
            Ji2 = ws[WS_ST + 8 * NPI + slot];
            Ji3 = ws[WS_ST + 9 * NPI + slot]; Ji4 = ws[WS_ST + 10 * NPI + slot];
            Ji5 = ws[WS_ST + 11 * NPI + slot];
            Ji6 = ws[WS_ST + 12 * NPI + slot]; Ji7 = ws[WS_ST + 13 * NPI + slot];
            Ji8 = ws[WS_ST + 14 * NPI + slot];
            // pending update (bit-identical to phase A's u expression)
            u0 = -(Ji0 * g0 + Ji1 * g1 + Ji2 * g2);
            u1 = -(Ji3 * g0 + Ji4 * g1 + Ji5 * g2);
            u2 = -(Ji6 * g0 + Ji7 * g1 + Ji8 * g2);
            bx0 = ws[WS_BX + pi * 3 + 0]; bx1 = ws[WS_BX + pi * 3 + 1];
            bx2 = ws[WS_BX + pi * 3 + 2];
            berr = ws[WS_BE + pi];
            const int pp = pi / NIB;
            tx = xd[pp * 3 + 0]; ty = xd[pp * 3 + 1]; tz = xd[pp * 3 + 2];
        }
#pragma unroll
        for (int cc = 0; cc < NCD; cc++) sIN[tid][3 + cc] = cond[batch * NCD + cc];
        sIN[tid][0] = 0; sIN[tid][1] = 0; sIN[tid][2] = 0;
    }

#pragma unroll 1
    for (int it = 0; it < MAX_STEPS; ++it) {
        bool active = false;
        float dx0 = 0, dx1 = 0, dx2 = 0;
        if (tid < 64) {
            active = realrow && (itleft > 0) && !(berr < CVG_EPS);
            if (active) {
                dx0 = u0; dx1 = u1; dx2 = u2;
                x0_ += dx0; x1_ += dx1; x2_ += dx2;
            }
            sIN[tid][0] = x0_; sIN[tid][1] = x1_; sIN[tid][2] = x2_;
        }
        __syncthreads();

        val_layer<19, INSTRD>(lw0, lb0, &sIN[0][0], sH, r, jb, false);
        val_layer<NHID, HSTR>(lw1, lb1, &sH[0][0], sH, r, jb, true);
        val_layer<NHID, HSTR>(lw2, lb2, &sH[0][0], sH, r, jb, true);
        logit_layer<false>(lw3, lb3, &sH[0][0], sLg, r, wid);

        if (tid < 64) {
            if (active) {
                broyden_step(&sLg[r][0], sTm, tx, ty, tz, dx0, dx1, dx2,
                             x0_, x1_, x2_, g0, g1, g2,
                             Ji0, Ji1, Ji2, Ji3, Ji4, Ji5, Ji6, Ji7, Ji8,
                             u0, u1, u2, bx0, bx1, bx2, berr);
                itleft--;
            }
            unsigned long long m =
                __ballot(realrow && (itleft > 0) && !(berr < CVG_EPS));
            if (tid == 0) sCnt = (int)__popcll(m);
        }
        __syncthreads();
        if (sCnt == 0) break;
    }

    if (tid < 64 && realrow) {
        ws[WS_BX + pi * 3 + 0] = bx0;
        ws[WS_BX + pi * 3 + 1] = bx1;
        ws[WS_BX + pi * 3 + 2] = bx2;
        ws[WS_BE + pi] = berr;
    }
}

// ---------------------------------------------------------------------------
// Phase C: disp MLP + f32 output for all problems.
// ---------------------------------------------------------------------------
__global__ __launch_bounds__(512) void kernel_c(
    const float* __restrict__ cond,
    const float* __restrict__ dw0, const float* __restrict__ db0,
    const float* __restrict__ dw1, const float* __restrict__ db1,
    const float* __restrict__ dw2, const float* __restrict__ db2,
    const float* __restrict__ dw3, const float* __restrict__ db3,
    const float* __restrict__ ws, float* __restrict__ out) {
    __shared__ float sIN[64][INSTRD];
    __shared__ float sH[64][HSTR];

    const int tid = threadIdx.x;
    const int r = tid & 63;
    const int wid = __builtin_amdgcn_readfirstlane(tid >> 6);
    const int jb = wid * 16;
    const int pi0 = blockIdx.x * 64;
    const int b = pi0 / NBSTRIDE;
    const int pi = pi0 + r;

    float bx0 = 0, bx1 = 0, bx2 = 0, berr = 0;
    if (tid < 64) {
        bx0 = ws[WS_BX + pi * 3 + 0]; bx1 = ws[WS_BX + pi * 3 + 1];
        bx2 = ws[WS_BX + pi * 3 + 2];
        berr = ws[WS_BE + pi];
        sIN[tid][0] = bx0; sIN[tid][1] = bx1; sIN[tid][2] = bx2;
#pragma unroll
        for (int cc = 0; cc < NCD; cc++) sIN[tid][3 + cc] = cond[b * NCD + cc];
    }
    __syncthreads();

    val_layer<19, INSTRD>(dw0, db0, &sIN[0][0], sH, r, jb, false);
    val_layer<NHID, HSTR>(dw1, db1, &sH[0][0], sH, r, jb, true);
    val_layer<NHID, HSTR>(dw2, db2, &sH[0][0], sH, r, jb, true);

    if (tid < 64) {
        float a0 = db3[0], a1 = db3[1], a2 = db3[2];
#pragma unroll 4
        for (int k = 0; k < NHID; k++) {
            float h = sH[tid][k];
            a0 = fmaf(h, dw3[k * 3 + 0], a0);
            a1 = fmaf(h, dw3[k * 3 + 1], a1);
            a2 = fmaf(h, dw3[k * 3 + 2], a2);
        }
        out[pi * 3 + 0] = bx0 + a0;
        out[pi * 3 + 1] = bx1 + a1;
        out[pi * 3 + 2] = bx2 + a2;
        out[3 * NPI + pi] = (berr < CVG_EPS) ? 1.0f : 0.0f;
    }
}

extern "C" void kernel_launch(void* const* d_in, const int* in_sizes, int n_in,
                              void* d_out, int out_size, void* d_ws, size_t ws_size,
                              hipStream_t stream) {
    (void)in_sizes; (void)n_in; (void)out_size; (void)ws_size;
    const float* xd   = (const float*)d_in[0];
    const float* cond = (const float*)d_in[1];
    const float* tfs  = (const float*)d_in[2];
    const float* lw0 = (const float*)d_in[3];  const float* lb0 = (const float*)d_in[4];
    const float* lw1 = (const float*)d_in[5];  const float* lb1 = (const float*)d_in[6];
    const float* lw2 = (const float*)d_in[7];  const float* lb2 = (const float*)d_in[8];
    const float* lw3 = (const float*)d_in[9];  const float* lb3 = (const float*)d_in[10];
    const float* dw0 = (const float*)d_in[11]; const float* db0 = (const float*)d_in[12];
    const float* dw1 = (const float*)d_in[13]; const float* db1 = (const float*)d_in[14];
    const float* dw2 = (const float*)d_in[15]; const float* db2 = (const float*)d_in[16];
    const float* dw3 = (const float*)d_in[17]; const float* db3 = (const float*)d_in[18];
    float* ws = (float*)d_ws;
    float* out = (float*)d_out;

    hipMemsetAsync(d_ws, 0, 16, stream);  // reset survivor counters (capture-safe)
    kernel_a<<<NPI / 64, 512, 0, stream>>>(xd, cond, tfs, lw0, lb0, lw1, lb1, lw2, lb2,
                                           lw3, lb3, ws);
    kernel_b<<<576, 512, 0, stream>>>(xd, cond, tfs, lw0, lb0, lw1, lb1, lw2, lb2,
                                      lw3, lb3, ws);
    kernel_c<<<NPI / 64, 512, 0, stream>>>(cond, dw0, db0, dw1, db1, dw2, db2, dw3, db3,
                                           ws, out);
}

// Round 6
// 1244.067 us; speedup vs baseline: 1.2046x; 1.0022x over previous
//
#include <hip/hip_runtime.h>
#include <math.h>

// Problem constants (from reference)
#define NB 2
#define NN 2048
#define NJ 24
#define NIB 9
#define NCD 16
#define NHID 128
#define NP (NB * NN)        // 4096
#define NPI (NP * NIB)      // 36864
#define NBSTRIDE (NN * NIB) // 18432 per batch
#define SBLEND 20.0f
#define CVG_EPS 1e-5f
#define MAX_STEPS 50
#define N_A 12              // Broyden iterations executed in phase A

// LDS strides (gcd(stride,32)==1 -> conflict-free column reads)
#define HSTR 129
#define INSTRD 21
#define LSTR 25

// ws layout (float offsets). cnt ints at [0,1]; ~2.95 MB total.
#define WS_BX 4
#define WS_BE (4 + 3 * NPI)
#define WS_META (4 + 4 * NPI)  // int region, NPI entries
#define WS_ST (4 + 5 * NPI)    // 15 components x NPI (SoA)

static __device__ __forceinline__ float softplusf(float x) {
    return fmaxf(x, 0.0f) + log1pf(expf(-fabsf(x)));
}
static __device__ __forceinline__ float sigmoidf(float x) {
    return 1.0f / (1.0f + expf(-x));
}
// init-bone index: {0,1,2,4,5,16,17,18,19}
static __device__ __forceinline__ int bone_of(int ib) {
    return (ib < 3) ? ib : ((ib < 5) ? ib + 1 : ib + 11);
}

// acc[0..15] += sum_k inrow[k] * W[k*NHID + jb + jj]  (wave-uniform W -> s_load)
template <int K>
static __device__ __forceinline__ void mv_acc16(const float* __restrict__ Wp, const float* inrow,
                                                int jb, float* acc) {
#pragma unroll 4
    for (int k = 0; k < K; k++) {
        float h = inrow[k];
        const float* wk = Wp + k * NHID + jb;
#pragma unroll
        for (int jj = 0; jj < 16; jj++) acc[jj] = fmaf(h, wk[jj], acc[jj]);
    }
}

template <int K, int LDIN>
static __device__ __forceinline__ void val_layer(const float* __restrict__ Wp,
                                                 const float* __restrict__ bp,
                                                 const float* inbase, float (*Hs)[HSTR], int r,
                                                 int jb, bool prebar) {
    float acc[16];
#pragma unroll
    for (int jj = 0; jj < 16; jj++) acc[jj] = bp[jb + jj];
    mv_acc16<K>(Wp, inbase + r * LDIN, jb, acc);
    if (prebar) __syncthreads();
#pragma unroll
    for (int jj = 0; jj < 16; jj++) Hs[r][jb + jj] = softplusf(acc[jj]);
    __syncthreads();
}

// jacfwd layer: rows 0..15 = value (softplus), rows 16..63 = tangents (sigmoid(zv)*z)
template <int K, int LDIN>
static __device__ __forceinline__ void jac_layer(const float* __restrict__ Wp,
                                                 const float* __restrict__ bp,
                                                 const float* inbase, float (*Hs)[HSTR], int r,
                                                 int jb, bool prebar) {
    const bool isval = (r < 16);
    const int p = r & 15;
    float acc[16];
#pragma unroll
    for (int jj = 0; jj < 16; jj++) acc[jj] = isval ? bp[jb + jj] : 0.0f;
    mv_acc16<K>(Wp, inbase + r * LDIN, jb, acc);
    if (prebar) __syncthreads();
#pragma unroll
    for (int jj = 0; jj < 16; jj++) Hs[r][jb + jj] = acc[jj];  // publish raw z
    __syncthreads();
    float zv[16];
    if (!isval) {
#pragma unroll
        for (int jj = 0; jj < 16; jj++) zv[jj] = Hs[p][jb + jj];
    }
    __syncthreads();
    if (isval) {
#pragma unroll
        for (int jj = 0; jj < 16; jj++) Hs[r][jb + jj] = softplusf(acc[jj]);
    } else {
#pragma unroll
        for (int jj = 0; jj < 16; jj++) Hs[r][jb + jj] = sigmoidf(zv[jj]) * acc[jj];
    }
    __syncthreads();
}

// final LBS layer (128 -> 24 logits), 3 cols per wave (8 waves)
template <bool JAC>
static __device__ __forceinline__ void logit_layer(const float* __restrict__ Wp,
                                                   const float* __restrict__ bp,
                                                   const float* inbase, float (*Lgs)[LSTR], int r,
                                                   int wid) {
    const int jb = wid * 3;
    const bool isval = (!JAC) || (r < 16);
    float acc[3];
#pragma unroll
    for (int jj = 0; jj < 3; jj++) acc[jj] = isval ? bp[jb + jj] : 0.0f;
#pragma unroll 4
    for (int k = 0; k < NHID; k++) {
        float h = inbase[r * HSTR + k];
        const float* wk = Wp + k * NJ + jb;
#pragma unroll
        for (int jj = 0; jj < 3; jj++) acc[jj] = fmaf(h, wk[jj], acc[jj]);
    }
#pragma unroll
    for (int jj = 0; jj < 3; jj++) Lgs[r][jb + jj] = acc[jj];
    __syncthreads();
}

// One Broyden update from logits in sLgRow (row r). Returns via refs.
static __device__ __forceinline__ void broyden_step(
    float* sLgRow, const float* sTm, float tx, float ty, float tz,
    float dx0, float dx1, float dx2,
    float& x0_, float& x1_, float& x2_, float& g0, float& g1, float& g2,
    float& Ji0, float& Ji1, float& Ji2, float& Ji3, float& Ji4, float& Ji5,
    float& Ji6, float& Ji7, float& Ji8,
    float& u0, float& u1, float& u2,
    float& bx0, float& bx1, float& bx2, float& berr) {
    float mx = -1e30f;
#pragma unroll
    for (int j = 0; j < NJ; j++) mx = fmaxf(mx, SBLEND * sLgRow[j]);
    float S = 0.0f;
#pragma unroll
    for (int j = 0; j < NJ; j++) {
        float e = expf(SBLEND * sLgRow[j] - mx);
        sLgRow[j] = e;
        S += e;
    }
    const float invS = 1.0f / S;
    float f0 = 0, f1 = 0, f2 = 0;
#pragma unroll
    for (int j = 0; j < NJ; j++) {
        float sj = sLgRow[j] * invS;
        const float* M = &sTm[j * 12];
        f0 += sj * (M[0] * x0_ + M[1] * x1_ + M[2] * x2_ + M[3]);
        f1 += sj * (M[4] * x0_ + M[5] * x1_ + M[6] * x2_ + M[7]);
        f2 += sj * (M[8] * x0_ + M[9] * x1_ + M[10] * x2_ + M[11]);
    }
    float gn0 = f0 - tx, gn1 = f1 - ty, gn2 = f2 - tz;
    float dg0 = gn0 - g0, dg1 = gn1 - g1, dg2 = gn2 - g2;
    float Jd0 = Ji0 * dg0 + Ji1 * dg1 + Ji2 * dg2;
    float Jd1 = Ji3 * dg0 + Ji4 * dg1 + Ji5 * dg2;
    float Jd2 = Ji6 * dg0 + Ji7 * dg1 + Ji8 * dg2;
    float v0 = dx0 * Ji0 + dx1 * Ji3 + dx2 * Ji6;
    float v1 = dx0 * Ji1 + dx1 * Ji4 + dx2 * Ji7;
    float v2 = dx0 * Ji2 + dx1 * Ji5 + dx2 * Ji8;
    float a0 = dx0 - Jd0, a1 = dx1 - Jd1, a2 = dx2 - Jd2;
    float bden = v0 * dg0 + v1 * dg1 + v2 * dg2 + 1e-6f;
    float s0 = a0 / bden, s1 = a1 / bden, s2 = a2 / bden;
    Ji0 += s0 * v0; Ji1 += s0 * v1; Ji2 += s0 * v2;
    Ji3 += s1 * v0; Ji4 += s1 * v1; Ji5 += s1 * v2;
    Ji6 += s2 * v0; Ji7 += s2 * v1; Ji8 += s2 * v2;
    u0 = -(Ji0 * gn0 + Ji1 * gn1 + Ji2 * gn2);
    u1 = -(Ji3 * gn0 + Ji4 * gn1 + Ji5 * gn2);
    u2 = -(Ji6 * gn0 + Ji7 * gn1 + Ji8 * gn2);
    float err = sqrtf(gn0 * gn0 + gn1 * gn1 + gn2 * gn2);
    if (err < berr) { berr = err; bx0 = x0_; bx1 = x1_; bx2 = x2_; }
    g0 = gn0; g1 = gn1; g2 = gn2;
}

// ---------------------------------------------------------------------------
// Phase A: init + at most N_A Broyden iterations (early exit only if ALL 64
// rows converge). All unconverged rows are offloaded (compacted) for phase B.
// 512 threads = 64 rows x 8 col-waves of 16.
// ---------------------------------------------------------------------------
__global__ __launch_bounds__(512) void kernel_a(
    const float* __restrict__ xd, const float* __restrict__ cond, const float* __restrict__ tfs,
    const float* __restrict__ lw0, const float* __restrict__ lb0,
    const float* __restrict__ lw1, const float* __restrict__ lb1,
    const float* __restrict__ lw2, const float* __restrict__ lb2,
    const float* __restrict__ lw3, const float* __restrict__ lb3,
    float* __restrict__ ws) {
    __shared__ float sIN[64][INSTRD];
    __shared__ float sH[64][HSTR];
    __shared__ float sLg[64][LSTR];
    __shared__ float sTm[NJ * 12];
    __shared__ int sCnt;

    const int tid = threadIdx.x;
    const int r = tid & 63;
    const int wid = __builtin_amdgcn_readfirstlane(tid >> 6);
    const int jb = wid * 16;
    const int pi0 = blockIdx.x * 64;
    const int b = pi0 / NBSTRIDE;
    const int pi = pi0 + r;

    for (int t = tid; t < NJ * 12; t += 512) {
        int j = t / 12, rc = t % 12;
        sTm[t] = tfs[(size_t)(b * NJ + j) * 16 + rc];
    }
    if (tid >= 16 && tid < 64) {  // tangent one-hot rows for init passes
        const int d = (tid >> 4) - 1;
#pragma unroll
        for (int k = 0; k < 19; k++) sIN[tid][k] = (k == d) ? 1.0f : 0.0f;
    }
    if (tid < 16) {
#pragma unroll
        for (int cc = 0; cc < NCD; cc++) sIN[tid][3 + cc] = cond[b * NCD + cc];
    }

    float x0_ = 0, x1_ = 0, x2_ = 0, g0 = 0, g1 = 0, g2 = 0;
    float Ji0 = 0, Ji1 = 0, Ji2 = 0, Ji3 = 0, Ji4 = 0, Ji5 = 0, Ji6 = 0, Ji7 = 0, Ji8 = 0;
    float u0 = 0, u1 = 0, u2 = 0, bx0 = 0, bx1 = 0, bx2 = 0, berr = 0;
    float tx = 0, ty = 0, tz = 0;
    if (tid < 64) {
        const int pp = pi / NIB;
        tx = xd[pp * 3 + 0]; ty = xd[pp * 3 + 1]; tz = xd[pp * 3 + 2];
    }

    // ---- init: 4 jacfwd passes of 16 points ----
#pragma unroll 1
    for (int pass = 0; pass < 4; ++pass) {
        __syncthreads();
        if (tid < 64 && (tid >> 4) == pass) {
            const int p = tid & 15;
            const int ib = pi % NIB;
            const float* T = tfs + (size_t)(b * NJ + bone_of(ib)) * 16;
            float r00 = T[0], r01 = T[1], r02 = T[2], t0 = T[3];
            float r10 = T[4], r11 = T[5], r12 = T[6], t1 = T[7];
            float r20 = T[8], r21 = T[9], r22 = T[10], t2 = T[11];
            float det = r00 * (r11 * r22 - r12 * r21) - r01 * (r10 * r22 - r12 * r20) +
                        r02 * (r10 * r21 - r11 * r20);
            float rd = 1.0f / det;
            float i00 = (r11 * r22 - r12 * r21) * rd, i01 = -(r01 * r22 - r02 * r21) * rd,
                  i02 = (r01 * r12 - r02 * r11) * rd;
            float i10 = -(r10 * r22 - r12 * r20) * rd, i11 = (r00 * r22 - r02 * r20) * rd,
                  i12 = -(r00 * r12 - r02 * r10) * rd;
            float i20 = (r10 * r21 - r11 * r20) * rd, i21 = -(r00 * r21 - r01 * r20) * rd,
                  i22 = (r00 * r11 - r01 * r10) * rd;
            float vx = tx - t0, vy = ty - t1, vz = tz - t2;
            x0_ = i00 * vx + i01 * vy + i02 * vz;
            x1_ = i10 * vx + i11 * vy + i12 * vz;
            x2_ = i20 * vx + i21 * vy + i22 * vz;
            sIN[p][0] = x0_; sIN[p][1] = x1_; sIN[p][2] = x2_;
        }
        __syncthreads();

        jac_layer<19, INSTRD>(lw0, lb0, &sIN[0][0], sH, r, jb, false);
        jac_layer<NHID, HSTR>(lw1, lb1, &sH[0][0], sH, r, jb, true);
        jac_layer<NHID, HSTR>(lw2, lb2, &sH[0][0], sH, r, jb, true);
        logit_layer<true>(lw3, lb3, &sH[0][0], sLg, r, wid);

        if (tid < 64 && (tid >> 4) == pass) {
            const int p = tid & 15;
            float mx = -1e30f;
#pragma unroll
            for (int j = 0; j < NJ; j++) mx = fmaxf(mx, SBLEND * sLg[p][j]);
            float S = 0.0f;
#pragma unroll
            for (int j = 0; j < NJ; j++) S += expf(SBLEND * sLg[p][j] - mx);
            const float invS = 1.0f / S;
            float d0 = 0, d1 = 0, d2 = 0;
#pragma unroll
            for (int j = 0; j < NJ; j++) {
                float sj = expf(SBLEND * sLg[p][j] - mx) * invS;
                d0 += sj * (SBLEND * sLg[16 + p][j]);
                d1 += sj * (SBLEND * sLg[32 + p][j]);
                d2 += sj * (SBLEND * sLg[48 + p][j]);
            }
            float f0 = 0, f1 = 0, f2 = 0;
            float J00 = 0, J01 = 0, J02 = 0, J10 = 0, J11 = 0, J12 = 0, J20 = 0, J21 = 0,
                  J22 = 0;
#pragma unroll
            for (int j = 0; j < NJ; j++) {
                float sj = expf(SBLEND * sLg[p][j] - mx) * invS;
                float uj0 = SBLEND * sLg[16 + p][j], uj1 = SBLEND * sLg[32 + p][j],
                      uj2 = SBLEND * sLg[48 + p][j];
                float sd0 = sj * (uj0 - d0), sd1 = sj * (uj1 - d1), sd2 = sj * (uj2 - d2);
                const float* M = &sTm[j * 12];
                float y0 = M[0] * x0_ + M[1] * x1_ + M[2] * x2_ + M[3];
                float y1 = M[4] * x0_ + M[5] * x1_ + M[6] * x2_ + M[7];
                float y2 = M[8] * x0_ + M[9] * x1_ + M[10] * x2_ + M[11];
                f0 += sj * y0; f1 += sj * y1; f2 += sj * y2;
                J00 += sd0 * y0 + sj * M[0]; J01 += sd1 * y0 + sj * M[1]; J02 += sd2 * y0 + sj * M[2];
                J10 += sd0 * y1 + sj * M[4]; J11 += sd1 * y1 + sj * M[5]; J12 += sd2 * y1 + sj * M[6];
                J20 += sd0 * y2 + sj * M[8]; J21 += sd1 * y2 + sj * M[9]; J22 += sd2 * y2 + sj * M[10];
            }
            g0 = f0 - tx; g1 = f1 - ty; g2 = f2 - tz;
            float detJ = J00 * (J11 * J22 - J12 * J21) - J01 * (J10 * J22 - J12 * J20) +
                         J02 * (J10 * J21 - J11 * J20);
            float rdJ = 1.0f / detJ;
            Ji0 = (J11 * J22 - J12 * J21) * rdJ; Ji1 = -(J01 * J22 - J02 * J21) * rdJ;
            Ji2 = (J01 * J12 - J02 * J11) * rdJ;
            Ji3 = -(J10 * J22 - J12 * J20) * rdJ; Ji4 = (J00 * J22 - J02 * J20) * rdJ;
            Ji5 = -(J00 * J12 - J02 * J10) * rdJ;
            Ji6 = (J10 * J21 - J11 * J20) * rdJ; Ji7 = -(J00 * J21 - J01 * J20) * rdJ;
            Ji8 = (J00 * J11 - J01 * J10) * rdJ;
            u0 = -(Ji0 * g0 + Ji1 * g1 + Ji2 * g2);
            u1 = -(Ji3 * g0 + Ji4 * g1 + Ji5 * g2);
            u2 = -(Ji6 * g0 + Ji7 * g1 + Ji8 * g2);
            berr = sqrtf(g0 * g0 + g1 * g1 + g2 * g2);
            bx0 = x0_; bx1 = x1_; bx2 = x2_;
        }
    }

    // ---- Broyden: at most N_A iterations in this phase ----
    if (tid < 64) {
#pragma unroll
        for (int cc = 0; cc < NCD; cc++) sIN[tid][3 + cc] = cond[b * NCD + cc];
    }

    int itdone = 0;
#pragma unroll 1
    for (int it = 0; it < N_A; ++it) {
        float dx0 = 0, dx1 = 0, dx2 = 0;
        if (tid < 64) {
            dx0 = u0; dx1 = u1; dx2 = u2;
            x0_ += dx0; x1_ += dx1; x2_ += dx2;
            sIN[tid][0] = x0_; sIN[tid][1] = x1_; sIN[tid][2] = x2_;
        }
        __syncthreads();

        val_layer<19, INSTRD>(lw0, lb0, &sIN[0][0], sH, r, jb, false);
        val_layer<NHID, HSTR>(lw1, lb1, &sH[0][0], sH, r, jb, true);
        val_layer<NHID, HSTR>(lw2, lb2, &sH[0][0], sH, r, jb, true);
        logit_layer<false>(lw3, lb3, &sH[0][0], sLg, r, wid);

        if (tid < 64) {
            broyden_step(&sLg[r][0], sTm, tx, ty, tz, dx0, dx1, dx2,
                         x0_, x1_, x2_, g0, g1, g2,
                         Ji0, Ji1, Ji2, Ji3, Ji4, Ji5, Ji6, Ji7, Ji8,
                         u0, u1, u2, bx0, bx1, bx2, berr);
            unsigned long long m = __ballot(!(berr < CVG_EPS));
            if (tid == 0) sCnt = (int)__popcll(m);
        }
        __syncthreads();
        itdone = it + 1;
        if (sCnt == 0) break;  // whole block converged early
    }

    if (tid < 64) {
        ws[WS_BX + pi * 3 + 0] = bx0;
        ws[WS_BX + pi * 3 + 1] = bx1;
        ws[WS_BX + pi * 3 + 2] = bx2;
        ws[WS_BE + pi] = berr;
        const int remaining = MAX_STEPS - itdone;
        if (remaining > 0 && !(berr < CVG_EPS)) {
            int idx = atomicAdd((int*)ws + b, 1);
            int slot = b * NBSTRIDE + idx;
            ((int*)ws)[WS_META + slot] = pi | (remaining << 20);
            float st[15] = {x0_, x1_, x2_, g0, g1, g2, Ji0, Ji1, Ji2, Ji3, Ji4, Ji5, Ji6, Ji7, Ji8};
#pragma unroll
            for (int c = 0; c < 15; c++) ws[WS_ST + c * NPI + slot] = st[c];
        }
    }
}

// ---------------------------------------------------------------------------
// Phase B: compacted stragglers, 64 per block, per-row remaining-iteration mask.
// Grid: 576 blocks; first 288 serve batch 0, rest batch 1.
// ---------------------------------------------------------------------------
__global__ __launch_bounds__(512) void kernel_b(
    const float* __restrict__ xd, const float* __restrict__ cond, const float* __restrict__ tfs,
    const float* __restrict__ lw0, const float* __restrict__ lb0,
    const float* __restrict__ lw1, const float* __restrict__ lb1,
    const float* __restrict__ lw2, const float* __restrict__ lb2,
    const float* __restrict__ lw3, const float* __restrict__ lb3,
    float* __restrict__ ws) {
    const int bid = blockIdx.x;
    const int batch = (bid < 288) ? 0 : 1;
    const int chunk0 = (bid - batch * 288) * 64;
    const int S = ((const int*)ws)[batch];
    if (chunk0 >= S) return;  // uniform per block, before any barrier

    __shared__ float sIN[64][INSTRD];
    __shared__ float sH[64][HSTR];
    __shared__ float sLg[64][LSTR];
    __shared__ float sTm[NJ * 12];
    __shared__ int sCnt;

    const int tid = threadIdx.x;
    const int r = tid & 63;
    const int wid = __builtin_amdgcn_readfirstlane(tid >> 6);
    const int jb = wid * 16;

    for (int t = tid; t < NJ * 12; t += 512) {
        int j = t / 12, rc = t % 12;
        sTm[t] = tfs[(size_t)(batch * NJ + j) * 16 + rc];
    }

    float x0_ = 0, x1_ = 0, x2_ = 0, g0 = 0, g1 = 0, g2 = 0;
    float Ji0 = 1, Ji1 = 0, Ji2 = 0, Ji3 = 0, Ji4 = 1, Ji5 = 0, Ji6 = 0, Ji7 = 0, Ji8 = 1;
    float u0 = 0, u1 = 0, u2 = 0, bx0 = 0, bx1 = 0, bx2 = 0, berr = 0;
    float tx = 0, ty = 0, tz = 0;
    int pi = -1, itleft = 0;
    bool realrow = false;
    if (tid < 64) {
        const int k = chunk0 + r;
        realrow = (k < S);
        if (realrow) {
            const int slot = batch * NBSTRIDE + k;
            const int meta = ((const int*)ws)[WS_META + slot];
            pi = meta & 0xFFFFF;
            itleft = meta >> 20;
            x0_ = ws[WS_ST + 0 * NPI + slot]; x1_ = ws[WS_ST + 1 * NPI + slot];
            x2_ = ws[WS_ST + 2 * NPI + slot];
            g0 = ws[WS_ST + 3 * NPI + slot]; g1 = ws[WS_ST + 4 * NPI + slot];
            g2 = ws[WS_ST + 5 * NPI + slot];
            Ji0 = ws[WS_ST + 6 * NPI + slot]; Ji1 = ws[WS_ST + 7 * NPI + slot];
            Ji2 = ws[WS_ST + 8 * NPI + slot];
            Ji3 = ws[WS_ST + 9 * NPI + slot]; Ji4 = ws[WS_ST + 10 * NPI + slot];
            Ji5 = ws[WS_ST + 11 * NPI + slot];
            Ji6 = ws[WS_ST + 12 * NPI + slot]; Ji7 = ws[WS_ST + 13 * NPI + slot];
            Ji8 = ws[WS_ST + 14 * NPI + slot];
            // pending update (bit-identical to phase A's u expression)
            u0 = -(Ji0 * g0 + Ji1 * g1 + Ji2 * g2);
            u1 = -(Ji3 * g0 + Ji4 * g1 + Ji5 * g2);
            u2 = -(Ji6 * g0 + Ji7 * g1 + Ji8 * g2);
            bx0 = ws[WS_BX + pi * 3 + 0]; bx1 = ws[WS_BX + pi * 3 + 1];
            bx2 = ws[WS_BX + pi * 3 + 2];
            berr = ws[WS_BE + pi];
            const int pp = pi / NIB;
            tx = xd[pp * 3 + 0]; ty = xd[pp * 3 + 1]; tz = xd[pp * 3 + 2];
        }
#pragma unroll
        for (int cc = 0; cc < NCD; cc++) sIN[tid][3 + cc] = cond[batch * NCD + cc];
        sIN[tid][0] = 0; sIN[tid][1] = 0; sIN[tid][2] = 0;
    }

#pragma unroll 1
    for (int it = 0; it < MAX_STEPS; ++it) {
        bool active = false;
        float dx0 = 0, dx1 = 0, dx2 = 0;
        if (tid < 64) {
            active = realrow && (itleft > 0) && !(berr < CVG_EPS);
            if (active) {
                dx0 = u0; dx1 = u1; dx2 = u2;
                x0_ += dx0; x1_ += dx1; x2_ += dx2;
            }
            sIN[tid][0] = x0_; sIN[tid][1] = x1_; sIN[tid][2] = x2_;
        }
        __syncthreads();

        val_layer<19, INSTRD>(lw0, lb0, &sIN[0][0], sH, r, jb, false);
        val_layer<NHID, HSTR>(lw1, lb1, &sH[0][0], sH, r, jb, true);
        val_layer<NHID, HSTR>(lw2, lb2, &sH[0][0], sH, r, jb, true);
        logit_layer<false>(lw3, lb3, &sH[0][0], sLg, r, wid);

        if (tid < 64) {
            if (active) {
                broyden_step(&sLg[r][0], sTm, tx, ty, tz, dx0, dx1, dx2,
                             x0_, x1_, x2_, g0, g1, g2,
                             Ji0, Ji1, Ji2, Ji3, Ji4, Ji5, Ji6, Ji7, Ji8,
                             u0, u1, u2, bx0, bx1, bx2, berr);
                itleft--;
            }
            unsigned long long m =
                __ballot(realrow && (itleft > 0) && !(berr < CVG_EPS));
            if (tid == 0) sCnt = (int)__popcll(m);
        }
        __syncthreads();
        if (sCnt == 0) break;
    }

    if (tid < 64 && realrow) {
        ws[WS_BX + pi * 3 + 0] = bx0;
        ws[WS_BX + pi * 3 + 1] = bx1;
        ws[WS_BX + pi * 3 + 2] = bx2;
        ws[WS_BE + pi] = berr;
    }
}

// ---------------------------------------------------------------------------
// Phase C: disp MLP + f32 output for all problems.
// ---------------------------------------------------------------------------
__global__ __launch_bounds__(512) void kernel_c(
    const float* __restrict__ cond,
    const float* __restrict__ dw0, const float* __restrict__ db0,
    const float* __restrict__ dw1, const float* __restrict__ db1,
    const float* __restrict__ dw2, const float* __restrict__ db2,
    const float* __restrict__ dw3, const float* __restrict__ db3,
    const float* __restrict__ ws, float* __restrict__ out) {
    __shared__ float sIN[64][INSTRD];
    __shared__ float sH[64][HSTR];

    const int tid = threadIdx.x;
    const int r = tid & 63;
    const int wid = __builtin_amdgcn_readfirstlane(tid >> 6);
    const int jb = wid * 16;
    const int pi0 = blockIdx.x * 64;
    const int b = pi0 / NBSTRIDE;
    const int pi = pi0 + r;

    float bx0 = 0, bx1 = 0, bx2 = 0, berr = 0;
    if (tid < 64) {
        bx0 = ws[WS_BX + pi * 3 + 0]; bx1 = ws[WS_BX + pi * 3 + 1];
        bx2 = ws[WS_BX + pi * 3 + 2];
        berr = ws[WS_BE + pi];
        sIN[tid][0] = bx0; sIN[tid][1] = bx1; sIN[tid][2] = bx2;
#pragma unroll
        for (int cc = 0; cc < NCD; cc++) sIN[tid][3 + cc] = cond[b * NCD + cc];
    }
    __syncthreads();

    val_layer<19, INSTRD>(dw0, db0, &sIN[0][0], sH, r, jb, false);
    val_layer<NHID, HSTR>(dw1, db1, &sH[0][0], sH, r, jb, true);
    val_layer<NHID, HSTR>(dw2, db2, &sH[0][0], sH, r, jb, true);

    if (tid < 64) {
        float a0 = db3[0], a1 = db3[1], a2 = db3[2];
#pragma unroll 4
        for (int k = 0; k < NHID; k++) {
            float h = sH[tid][k];
            a0 = fmaf(h, dw3[k * 3 + 0], a0);
            a1 = fmaf(h, dw3[k * 3 + 1], a1);
            a2 = fmaf(h, dw3[k * 3 + 2], a2);
        }
        out[pi * 3 + 0] = bx0 + a0;
        out[pi * 3 + 1] = bx1 + a1;
        out[pi * 3 + 2] = bx2 + a2;
        out[3 * NPI + pi] = (berr < CVG_EPS) ? 1.0f : 0.0f;
    }
}

extern "C" void kernel_launch(void* const* d_in, const int* in_sizes, int n_in,
                              void* d_out, int out_size, void* d_ws, size_t ws_size,
                              hipStream_t stream) {
    (void)in_sizes; (void)n_in; (void)out_size; (void)ws_size;
    const float* xd   = (const float*)d_in[0];
    const float* cond = (const float*)d_in[1];
    const float* tfs  = (const float*)d_in[2];
    const float* lw0 = (const float*)d_in[3];  const float* lb0 = (const float*)d_in[4];
    const float* lw1 = (const float*)d_in[5];  const float* lb1 = (const float*)d_in[6];
    const float* lw2 = (const float*)d_in[7];  const float* lb2 = (const float*)d_in[8];
    const float* lw3 = (const float*)d_in[9];  const float* lb3 = (const float*)d_in[10];
    const float* dw0 = (const float*)d_in[11]; const float* db0 = (const float*)d_in[12];
    const float* dw1 = (const float*)d_in[13]; const float* db1 = (const float*)d_in[14];
    const float* dw2 = (const float*)d_in[15]; const float* db2 = (const float*)d_in[16];
    const float* dw3 = (const float*)d_in[17]; const float* db3 = (const float*)d_in[18];
    float* ws = (float*)d_ws;
    float* out = (float*)d_out;

    hipMemsetAsync(d_ws, 0, 16, stream);  // reset survivor counters (capture-safe)
    kernel_a<<<NPI / 64, 512, 0, stream>>>(xd, cond, tfs, lw0, lb0, lw1, lb1, lw2, lb2,
                                           lw3, lb3, ws);
    kernel_b<<<576, 512, 0, stream>>>(xd, cond, tfs, lw0, lb0, lw1, lb1, lw2, lb2,
                                      lw3, lb3, ws);
    kernel_c<<<NPI / 64, 512, 0, stream>>>(cond, dw0, db0, dw1, db1, dw2, db2, dw3, db3,
                                           ws, out);
}